// Round 3
// baseline (395.729 us; speedup 1.0000x reference)
//
#include <hip/hip_runtime.h>
#include <hip/hip_bf16.h>
#include <stdint.h>

typedef unsigned short u16;
typedef __attribute__((ext_vector_type(8))) short short8;
typedef __attribute__((ext_vector_type(4))) float float4v;

// RNE float->bf16
__device__ __forceinline__ u16 f2bf(float x) {
    union { float f; unsigned int u; } v; v.f = x;
    unsigned int r = v.u + 0x7fffu + ((v.u >> 16) & 1u);
    return (u16)(r >> 16);
}

__device__ __forceinline__ void ld_g2l16(const void* g, void* l) {
    __builtin_amdgcn_global_load_lds(
        (const __attribute__((address_space(1))) void*)g,
        (__attribute__((address_space(3))) void*)l, 16, 0, 0);
}

// ---------------- Pass 1: tables -> bf16 (16 floats/thread) + pack W1 ------------
// W1pack[kc][t][lane][j] = W1[kc*32 + (lane>>4)*8 + j][t*16 + (lane&15)]
__global__ __launch_bounds__(256) void conv_pack(
    const float* __restrict__ zs, const float* __restrict__ zt,
    const float* __restrict__ W1,
    u16* __restrict__ zs_b, u16* __restrict__ zt_b, u16* __restrict__ w1p,
    int n16s, int n16t)
{
    int id = blockIdx.x * 256 + threadIdx.x;
    if (id < n16s + n16t) {
        const float* src; u16* dst; int i;
        if (id < n16s) { src = zs; dst = zs_b; i = id; }
        else           { src = zt; dst = zt_b; i = id - n16s; }
        const float4* p = (const float4*)src + (size_t)i * 4;
        float4 a = p[0], b = p[1], c = p[2], d = p[3];
        short8 o0, o1;
        o0[0] = (short)f2bf(a.x); o0[1] = (short)f2bf(a.y);
        o0[2] = (short)f2bf(a.z); o0[3] = (short)f2bf(a.w);
        o0[4] = (short)f2bf(b.x); o0[5] = (short)f2bf(b.y);
        o0[6] = (short)f2bf(b.z); o0[7] = (short)f2bf(b.w);
        o1[0] = (short)f2bf(c.x); o1[1] = (short)f2bf(c.y);
        o1[2] = (short)f2bf(c.z); o1[3] = (short)f2bf(c.w);
        o1[4] = (short)f2bf(d.x); o1[5] = (short)f2bf(d.y);
        o1[6] = (short)f2bf(d.z); o1[7] = (short)f2bf(d.w);
        short8* q = (short8*)(dst + (size_t)i * 16);
        q[0] = o0; q[1] = o1;
    } else {
        int w = id - (n16s + n16t);
        if (w < 4096) {
            int lanep = w & 63, t = (w >> 6) & 7, kc = w >> 9;
            short8 o;
#pragma unroll
            for (int j = 0; j < 8; ++j) {
                int k = kc * 32 + (lanep >> 4) * 8 + j;
                int n = t * 16 + (lanep & 15);
                o[j] = (short)f2bf(W1[k * 128 + n]);
            }
            *(short8*)(w1p + (size_t)w * 8) = o;
        }
    }
}

// A-frag gather: lane m15 = edge-in-group, quad = 16B k-offset
__device__ __forceinline__ short8 loadA(
    const u16* __restrict__ zs, const u16* __restrict__ zt,
    const int* ridx, const int* cidx, int kc, int mtl, int quad)
{
    const u16* base = (kc < 4)
        ? zs + (size_t)(unsigned)ridx[mtl] * 128 + kc * 32
        : zt + (size_t)(unsigned)cidx[mtl] * 128 + (kc - 4) * 32;
    return *(const short8*)(base + quad * 8);
}

// ---------------- Pass 2: barrier-free gathered MFMA GEMM (slim tiles) -----------
// Persistent 512 blocks x 256 thr (2 blocks/CU via 64KB W1 LDS). Each wave
// grid-strides over 32-edge tiles: acc[2 mtl][8 ntl] = 64 regs, A gathered
// direct to VGPRs with 2-kc-deep double buffer (32 regs), B frags from LDS.
// Index + group-0 loads pipelined one full tile ahead. NO steady-state barriers.
__global__ __launch_bounds__(256, 2) void edge_mlp(
    const u16* __restrict__ zs, const u16* __restrict__ zt,
    const u16* __restrict__ w1p,
    const int* __restrict__ row, const int* __restrict__ col,
    const float* __restrict__ b1, const float* __restrict__ W2,
    const float* __restrict__ b2, float* __restrict__ out,
    int E, int nwaves)
{
    __shared__ u16 Blds[32768];   // 64 KB: full W1 in B-frag layout

    const int tid  = threadIdx.x;
    const int wave = tid >> 6, lane = tid & 63;
    const int m15 = lane & 15, quad = lane >> 4;

    // stage B once per (persistent) block
#pragma unroll
    for (int it = 0; it < 16; ++it) {
        int off = (wave * 16 + it) * 1024;
        ld_g2l16((const char*)w1p + off + lane * 16, (char*)Blds + off);
    }

    float b1v[8], w2v[8];
#pragma unroll
    for (int n = 0; n < 8; ++n) {
        b1v[n] = b1[n * 16 + m15];
        w2v[n] = W2[n * 16 + m15];
    }
    const float b2v = b2[0];

    __builtin_amdgcn_s_waitcnt(0);
    __syncthreads();

    const int T = (E + 31) >> 5;
    const int wgid = blockIdx.x * 4 + wave;
    if (wgid >= T) return;

    // indices for tile t (ridx/cidx) and tile t+nwaves (nridx/ncidx)
    int ridx[2], cidx[2], nridx[2], ncidx[2];
#pragma unroll
    for (int mtl = 0; mtl < 2; ++mtl) {
        int e = wgid * 32 + mtl * 16 + m15;
        e = e < E ? e : E - 1;
        ridx[mtl] = row[e]; cidx[mtl] = col[e];
    }
    {
        int tn = wgid + nwaves;
#pragma unroll
        for (int mtl = 0; mtl < 2; ++mtl) {
            int e = tn * 32 + mtl * 16 + m15;
            e = e < E ? e : E - 1;
            nridx[mtl] = row[e]; ncidx[mtl] = col[e];
        }
    }

    // preload group 0 (kc 0,1) of first tile
    short8 Abuf[2][2][2];   // [buf][kcin][mtl]
#pragma unroll
    for (int kcin = 0; kcin < 2; ++kcin)
#pragma unroll
        for (int mtl = 0; mtl < 2; ++mtl)
            Abuf[0][kcin][mtl] = loadA(zs, zt, ridx, cidx, kcin, mtl, quad);

    for (int t = wgid; t < T; t += nwaves) {
        float4v acc[2][8];
#pragma unroll
        for (int a = 0; a < 2; ++a)
#pragma unroll
            for (int b = 0; b < 8; ++b)
                acc[a][b] = (float4v){0.f, 0.f, 0.f, 0.f};

#pragma unroll
        for (int g = 0; g < 4; ++g) {
            const int b = g & 1, nb = b ^ 1;
            if (g < 3) {
                // prefetch next kc-group of this tile
#pragma unroll
                for (int kcin = 0; kcin < 2; ++kcin)
#pragma unroll
                    for (int mtl = 0; mtl < 2; ++mtl)
                        Abuf[nb][kcin][mtl] =
                            loadA(zs, zt, ridx, cidx, 2 * (g + 1) + kcin, mtl, quad);
            } else {
                // issue next TILE's group 0 (indices prefetched a tile ago)
                int tn = t + nwaves;
                if (tn < T) {
#pragma unroll
                    for (int kcin = 0; kcin < 2; ++kcin)
#pragma unroll
                        for (int mtl = 0; mtl < 2; ++mtl)
                            Abuf[nb][kcin][mtl] =
                                loadA(zs, zt, nridx, ncidx, kcin, mtl, quad);
                }
            }
            // compute this kc-group
#pragma unroll
            for (int kcin = 0; kcin < 2; ++kcin) {
                int kc = 2 * g + kcin;
#pragma unroll
                for (int j = 0; j < 8; ++j) {
                    short8 Bf = *(const short8*)(Blds + (size_t)((kc * 8 + j) * 64 + lane) * 8);
#pragma unroll
                    for (int mtl = 0; mtl < 2; ++mtl)
                        acc[mtl][j] = __builtin_amdgcn_mfma_f32_16x16x32_bf16(
                            Abuf[b][kcin][mtl], Bf, acc[mtl][j], 0, 0, 0);
                }
            }
        }

        // roll indices; prefetch tile t+2*nwaves indices (next-tile loads in flight)
#pragma unroll
        for (int mtl = 0; mtl < 2; ++mtl) {
            ridx[mtl] = nridx[mtl]; cidx[mtl] = ncidx[mtl];
        }
        {
            int tnn = t + 2 * nwaves;
            if (tnn < T) {
#pragma unroll
                for (int mtl = 0; mtl < 2; ++mtl) {
                    int e = tnn * 32 + mtl * 16 + m15;
                    e = e < E ? e : E - 1;
                    nridx[mtl] = row[e]; ncidx[mtl] = col[e];
                }
            }
        }

        // epilogue: +b1, relu, dot W2 (8 in-lane + 16-lane butterfly), store
#pragma unroll
        for (int mtl = 0; mtl < 2; ++mtl) {
            float4v part;
#pragma unroll
            for (int r = 0; r < 4; ++r) {
                float s = 0.f;
#pragma unroll
                for (int j = 0; j < 8; ++j) {
                    float h = acc[mtl][j][r] + b1v[j];
                    h = h > 0.f ? h : 0.f;
                    s = fmaf(h, w2v[j], s);
                }
                s += __shfl_xor(s, 1);
                s += __shfl_xor(s, 2);
                s += __shfl_xor(s, 4);
                s += __shfl_xor(s, 8);
                part[r] = s + b2v;
            }
            if (m15 == 0) {
                int e0 = t * 32 + mtl * 16 + quad * 4;
                if (e0 + 3 < E) {
                    *(float4v*)(out + e0) = part;
                } else {
#pragma unroll
                    for (int r = 0; r < 4; ++r)
                        if (e0 + r < E) out[e0 + r] = part[r];
                }
            }
        }
    }
}

// ---------------- Fallback (fp32, slow but correct) if workspace too small -------
__global__ __launch_bounds__(256) void edge_mlp_naive(
    const float* __restrict__ zs, const float* __restrict__ zt,
    const int* __restrict__ row, const int* __restrict__ col,
    const float* __restrict__ W1, const float* __restrict__ b1,
    const float* __restrict__ W2, const float* __restrict__ b2,
    float* __restrict__ out, int E)
{
    __shared__ float zr[4][256];
    int wave = threadIdx.x >> 6, lane = threadIdx.x & 63;
    int e = blockIdx.x * 4 + wave;
    int ec = e < E ? e : E - 1;
    const float* a = zs + (size_t)row[ec] * 128;
    const float* bb = zt + (size_t)col[ec] * 128;
    zr[wave][lane] = a[lane];
    zr[wave][64 + lane] = a[64 + lane];
    zr[wave][128 + lane] = bb[lane];
    zr[wave][192 + lane] = bb[64 + lane];
    __syncthreads();
    float h0 = b1[lane], h1 = b1[64 + lane];
    for (int k = 0; k < 256; ++k) {
        float zk = zr[wave][k];
        h0 = fmaf(zk, W1[k * 128 + lane], h0);
        h1 = fmaf(zk, W1[k * 128 + 64 + lane], h1);
    }
    h0 = h0 > 0.f ? h0 : 0.f;
    h1 = h1 > 0.f ? h1 : 0.f;
    float s = fmaf(h0, W2[lane], h1 * W2[64 + lane]);
    for (int m = 1; m < 64; m <<= 1) s += __shfl_xor(s, m);
    if (lane == 0 && e < E) out[e] = s + b2[0];
}

extern "C" void kernel_launch(void* const* d_in, const int* in_sizes, int n_in,
                              void* d_out, int out_size, void* d_ws, size_t ws_size,
                              hipStream_t stream) {
    const float* zs = (const float*)d_in[0];
    const float* zt = (const float*)d_in[1];
    const int*  row = (const int*)d_in[2];
    const int*  col = (const int*)d_in[3];
    const float* W1 = (const float*)d_in[4];
    const float* b1 = (const float*)d_in[5];
    const float* W2 = (const float*)d_in[6];
    const float* b2 = (const float*)d_in[7];
    float* out = (float*)d_out;

    const int nzs = in_sizes[0];       // 12,800,000
    const int nzt = in_sizes[1];       // 6,400,000
    const int E   = in_sizes[2];       // 1,000,000

    const size_t need = ((size_t)nzs + (size_t)nzt + 32768) * 2;
    if (ws_size < need) {
        int nb = (E + 3) / 4;
        edge_mlp_naive<<<nb, 256, 0, stream>>>(zs, zt, row, col, W1, b1, W2, b2, out, E);
        return;
    }

    u16* zs_b = (u16*)d_ws;
    u16* zt_b = zs_b + nzs;
    u16* w1p  = zt_b + nzt;

    const int n16s = nzs / 16, n16t = nzt / 16;
    const int convN = n16s + n16t + 4096;
    conv_pack<<<(convN + 255) / 256, 256, 0, stream>>>(zs, zt, W1, zs_b, zt_b, w1p, n16s, n16t);

    // persistent: 512 blocks = 2/CU (64KB LDS each), 2048 waves grid-striding
    const int nblocks = 512;
    const int nwaves = nblocks * 4;
    edge_mlp<<<nblocks, 256, 0, stream>>>(zs_b, zt_b, w1p, row, col, b1, W2, b2, out, E, nwaves);
}

// Round 4
// 251.394 us; speedup vs baseline: 1.5741x; 1.5741x over previous
//
#include <hip/hip_runtime.h>
#include <hip/hip_bf16.h>
#include <stdint.h>

typedef unsigned short u16;
typedef __attribute__((ext_vector_type(8))) short short8;
typedef __attribute__((ext_vector_type(4))) short short4v;
typedef __attribute__((ext_vector_type(4))) float float4v;

// RNE float->bf16
__device__ __forceinline__ u16 f2bf(float x) {
    union { float f; unsigned int u; } v; v.f = x;
    unsigned int r = v.u + 0x7fffu + ((v.u >> 16) & 1u);
    return (u16)(r >> 16);
}

__device__ __forceinline__ void ld_g2l16(const void* g, void* l) {
    __builtin_amdgcn_global_load_lds(
        (const __attribute__((address_space(1))) void*)g,
        (__attribute__((address_space(3))) void*)l, 16, 0, 0);
}

__device__ __forceinline__ void atomic_add_f32(float* p, float v) {
#if defined(__gfx90a__) || defined(__gfx940__) || defined(__gfx941__) || defined(__gfx942__) || defined(__gfx950__)
    unsafeAtomicAdd(p, v);
#else
    atomicAdd(p, v);
#endif
}

// ---------------- Pass 1: tables -> bf16 (coalesced, 1 float4/thread) + pack W1 --
// W1pack[kc][t][lane][j] = W1[kc*32 + (lane>>4)*8 + j][t*16 + (lane&15)]
__global__ __launch_bounds__(256) void conv_pack(
    const float* __restrict__ zs, const float* __restrict__ zt,
    const float* __restrict__ W1,
    u16* __restrict__ zs_b, u16* __restrict__ zt_b, u16* __restrict__ w1p,
    int n4s, int n4t)
{
    int id = blockIdx.x * 256 + threadIdx.x;
    int n4 = n4s + n4t;
    if (id < n4) {
        const float4* src; u16* dst; int i;
        if (id < n4s) { src = (const float4*)zs; dst = zs_b; i = id; }
        else          { src = (const float4*)zt; dst = zt_b; i = id - n4s; }
        float4 a = src[i];
        short4v o;
        o[0] = (short)f2bf(a.x); o[1] = (short)f2bf(a.y);
        o[2] = (short)f2bf(a.z); o[3] = (short)f2bf(a.w);
        *(short4v*)(dst + (size_t)i * 4) = o;
    } else {
        int w = id - n4;
        if (w < 4096) {
            int lanep = w & 63, t = (w >> 6) & 7, kc = w >> 9;
            short8 o;
#pragma unroll
            for (int j = 0; j < 8; ++j) {
                int k = kc * 32 + (lanep >> 4) * 8 + j;
                int n = t * 16 + (lanep & 15);
                o[j] = (short)f2bf(W1[k * 128 + n]);
            }
            *(short8*)(w1p + (size_t)w * 8) = o;
        }
    }
}

// A-frag gather: lane m15 = edge-in-group, quad = 16B k-offset
__device__ __forceinline__ short8 loadA(
    const u16* __restrict__ zs, const u16* __restrict__ zt,
    const int* ridx, const int* cidx, int kc, int mtl, int quad)
{
    const u16* base = (kc < 4)
        ? zs + (size_t)(unsigned)ridx[mtl] * 128 + kc * 32
        : zt + (size_t)(unsigned)cidx[mtl] * 128 + (kc - 4) * 32;
    return *(const short8*)(base + quad * 8);
}

// ---------------- Pass 2: barrier-free gathered MFMA GEMM, n split over wave pairs
// Persistent 512 blocks x 256 thr (2 blocks/CU via 64KB W1 LDS). Job = (tile, nh):
// wave handles 32 edges x 64 cols -> acc[2][4]=32 AGPR, Abuf dbuf 32 VGPR (~100
// arch VGPRs: no spill). Pair waves (same block) duplicate A gathers (L1 hit).
// Partial W2-dots combined via HW fp32 atomics onto zeroed out.
__global__ __launch_bounds__(256, 2) void edge_mlp(
    const u16* __restrict__ zs, const u16* __restrict__ zt,
    const u16* __restrict__ w1p,
    const int* __restrict__ row, const int* __restrict__ col,
    const float* __restrict__ b1, const float* __restrict__ W2,
    const float* __restrict__ b2, float* __restrict__ out,
    int E, int nwaves)
{
    __shared__ u16 Blds[32768];   // 64 KB: full W1 in B-frag layout

    const int tid  = threadIdx.x;
    const int wave = tid >> 6, lane = tid & 63;
    const int m15 = lane & 15, quad = lane >> 4;

    // stage B once per (persistent) block
#pragma unroll
    for (int it = 0; it < 16; ++it) {
        int off = (wave * 16 + it) * 1024;
        ld_g2l16((const char*)w1p + off + lane * 16, (char*)Blds + off);
    }

    const int wgid = blockIdx.x * 4 + wave;
    const int nh = wgid & 1;              // which n-half this wave owns
    const int t0 = wgid >> 1;
    const int tstride = nwaves >> 1;

    // per-lane epilogue params for this n-half: col = (nh*4+j)*16 + m15
    float b1v[4], w2v[4];
#pragma unroll
    for (int j = 0; j < 4; ++j) {
        b1v[j] = b1[((nh << 2) + j) * 16 + m15];
        w2v[j] = W2[((nh << 2) + j) * 16 + m15];
    }
    const float b2v = (nh == 0) ? b2[0] : 0.f;

    __builtin_amdgcn_s_waitcnt(0);
    __syncthreads();

    const int T = (E + 31) >> 5;
    if (t0 >= T) return;

    int ridx[2], cidx[2], nridx[2], ncidx[2];
#pragma unroll
    for (int mtl = 0; mtl < 2; ++mtl) {
        int e = t0 * 32 + mtl * 16 + m15;
        e = e < E ? e : E - 1;
        ridx[mtl] = row[e]; cidx[mtl] = col[e];
    }
    {
        int tn = t0 + tstride;
#pragma unroll
        for (int mtl = 0; mtl < 2; ++mtl) {
            int e = tn * 32 + mtl * 16 + m15;
            e = e < E ? e : E - 1;
            nridx[mtl] = row[e]; ncidx[mtl] = col[e];
        }
    }

    // preload group 0 (kc 0,1) of first tile
    short8 Abuf[2][2][2];   // [buf][kcin][mtl] : 32 VGPRs
#pragma unroll
    for (int kcin = 0; kcin < 2; ++kcin)
#pragma unroll
        for (int mtl = 0; mtl < 2; ++mtl)
            Abuf[0][kcin][mtl] = loadA(zs, zt, ridx, cidx, kcin, mtl, quad);

    for (int t = t0; t < T; t += tstride) {
        float4v acc[2][4];
#pragma unroll
        for (int a = 0; a < 2; ++a)
#pragma unroll
            for (int b = 0; b < 4; ++b)
                acc[a][b] = (float4v){0.f, 0.f, 0.f, 0.f};

#pragma unroll
        for (int g = 0; g < 4; ++g) {
            const int b = g & 1, nb = b ^ 1;
            if (g < 3) {
#pragma unroll
                for (int kcin = 0; kcin < 2; ++kcin)
#pragma unroll
                    for (int mtl = 0; mtl < 2; ++mtl)
                        Abuf[nb][kcin][mtl] =
                            loadA(zs, zt, ridx, cidx, 2 * (g + 1) + kcin, mtl, quad);
            } else {
                int tn = t + tstride;
                if (tn < T) {
#pragma unroll
                    for (int kcin = 0; kcin < 2; ++kcin)
#pragma unroll
                        for (int mtl = 0; mtl < 2; ++mtl)
                            Abuf[nb][kcin][mtl] =
                                loadA(zs, zt, nridx, ncidx, kcin, mtl, quad);
                }
            }
#pragma unroll
            for (int kcin = 0; kcin < 2; ++kcin) {
                int kc = 2 * g + kcin;
#pragma unroll
                for (int j = 0; j < 4; ++j) {
                    // frag id = kc*8 + nh*4 + j; contiguous 1KB per read: conflict-free
                    short8 Bf = *(const short8*)(Blds + (size_t)((kc * 8 + (nh << 2) + j) * 64 + lane) * 8);
#pragma unroll
                    for (int mtl = 0; mtl < 2; ++mtl)
                        acc[mtl][j] = __builtin_amdgcn_mfma_f32_16x16x32_bf16(
                            Abuf[b][kcin][mtl], Bf, acc[mtl][j], 0, 0, 0);
                }
            }
        }

        // roll indices; prefetch t+2*tstride
#pragma unroll
        for (int mtl = 0; mtl < 2; ++mtl) {
            ridx[mtl] = nridx[mtl]; cidx[mtl] = ncidx[mtl];
        }
        {
            int tnn = t + 2 * tstride;
            if (tnn < T) {
#pragma unroll
                for (int mtl = 0; mtl < 2; ++mtl) {
                    int e = tnn * 32 + mtl * 16 + m15;
                    e = e < E ? e : E - 1;
                    nridx[mtl] = row[e]; ncidx[mtl] = col[e];
                }
            }
        }

        // epilogue: +b1, relu, dot W2 over this n-half, 16-lane butterfly, atomic out
#pragma unroll
        for (int mtl = 0; mtl < 2; ++mtl) {
#pragma unroll
            for (int r = 0; r < 4; ++r) {
                float s = 0.f;
#pragma unroll
                for (int j = 0; j < 4; ++j) {
                    float h = acc[mtl][j][r] + b1v[j];
                    h = h > 0.f ? h : 0.f;
                    s = fmaf(h, w2v[j], s);
                }
                s += __shfl_xor(s, 1);
                s += __shfl_xor(s, 2);
                s += __shfl_xor(s, 4);
                s += __shfl_xor(s, 8);
                if (m15 == 0) {
                    int e = t * 32 + mtl * 16 + quad * 4 + r;
                    if (e < E) atomic_add_f32(out + e, s + b2v);
                }
            }
        }
    }
}

// ---------------- Fallback (fp32, slow but correct) if workspace too small -------
__global__ __launch_bounds__(256) void edge_mlp_naive(
    const float* __restrict__ zs, const float* __restrict__ zt,
    const int* __restrict__ row, const int* __restrict__ col,
    const float* __restrict__ W1, const float* __restrict__ b1,
    const float* __restrict__ W2, const float* __restrict__ b2,
    float* __restrict__ out, int E)
{
    __shared__ float zr[4][256];
    int wave = threadIdx.x >> 6, lane = threadIdx.x & 63;
    int e = blockIdx.x * 4 + wave;
    int ec = e < E ? e : E - 1;
    const float* a = zs + (size_t)row[ec] * 128;
    const float* bb = zt + (size_t)col[ec] * 128;
    zr[wave][lane] = a[lane];
    zr[wave][64 + lane] = a[64 + lane];
    zr[wave][128 + lane] = bb[lane];
    zr[wave][192 + lane] = bb[64 + lane];
    __syncthreads();
    float h0 = b1[lane], h1 = b1[64 + lane];
    for (int k = 0; k < 256; ++k) {
        float zk = zr[wave][k];
        h0 = fmaf(zk, W1[k * 128 + lane], h0);
        h1 = fmaf(zk, W1[k * 128 + 64 + lane], h1);
    }
    h0 = h0 > 0.f ? h0 : 0.f;
    h1 = h1 > 0.f ? h1 : 0.f;
    float s = fmaf(h0, W2[lane], h1 * W2[64 + lane]);
    for (int m = 1; m < 64; m <<= 1) s += __shfl_xor(s, m);
    if (lane == 0 && e < E) out[e] = s + b2[0];
}

extern "C" void kernel_launch(void* const* d_in, const int* in_sizes, int n_in,
                              void* d_out, int out_size, void* d_ws, size_t ws_size,
                              hipStream_t stream) {
    const float* zs = (const float*)d_in[0];
    const float* zt = (const float*)d_in[1];
    const int*  row = (const int*)d_in[2];
    const int*  col = (const int*)d_in[3];
    const float* W1 = (const float*)d_in[4];
    const float* b1 = (const float*)d_in[5];
    const float* W2 = (const float*)d_in[6];
    const float* b2 = (const float*)d_in[7];
    float* out = (float*)d_out;

    const int nzs = in_sizes[0];       // 12,800,000
    const int nzt = in_sizes[1];       // 6,400,000
    const int E   = in_sizes[2];       // 1,000,000

    const size_t need = ((size_t)nzs + (size_t)nzt + 32768) * 2;
    if (ws_size < need) {
        int nb = (E + 3) / 4;
        edge_mlp_naive<<<nb, 256, 0, stream>>>(zs, zt, row, col, W1, b1, W2, b2, out, E);
        return;
    }

    u16* zs_b = (u16*)d_ws;
    u16* zt_b = zs_b + nzs;
    u16* w1p  = zt_b + nzt;

    const int n4s = nzs / 4, n4t = nzt / 4;
    const int convN = n4s + n4t + 4096;
    conv_pack<<<(convN + 255) / 256, 256, 0, stream>>>(zs, zt, W1, zs_b, zt_b, w1p, n4s, n4t);

    // zero the output for atomic accumulation (async on stream: graph-capturable)
    hipMemsetAsync(out, 0, (size_t)E * sizeof(float), stream);

    // persistent: 512 blocks = 2/CU (64KB LDS each), 2048 waves over (tile, n-half) jobs
    const int nblocks = 512;
    const int nwaves = nblocks * 4;
    edge_mlp<<<nblocks, 256, 0, stream>>>(zs_b, zt_b, w1p, row, col, b1, W2, b2, out, E, nwaves);
}